// Round 12
// baseline (11238.553 us; speedup 1.0000x reference)
//
#include <hip/hip_runtime.h>
#include <stdint.h>

#define EFFECT_DIM 758
#define ADD_DIM 10
#define EMBED_DIM 768
#define NCOLS 95000
#define NSYN 8
#define NROWS 1024
#define TILE_B 32768         // bytes per 256x64 bf16 A tile (fragment-ordered)
#define NTN 372              // n-tiles of 256
#define NWG (2 * NTN)        // 744 blocks = 2 mt x 372 nt = 8 XCDs x 93

typedef __attribute__((ext_vector_type(8))) __bf16 bf16x8;
typedef __attribute__((ext_vector_type(16))) float f32x16;
typedef __attribute__((ext_vector_type(4))) uint32_t u32x4;

// Fragment order (16-k block): frag = 1KB, lane = (row&31) + (khalf8<<5),
// 16B/lane = 8 consecutive k as bf16. A tile (ws): tile(mtq,ks) at
// (mtq*12+ks)*32768; + kk*8192 + grp*1024 + lane*16.

static __device__ __forceinline__ uint32_t pack2(float a, float b) {
  uint32_t r;
  asm("v_cvt_pk_bf16_f32 %0, %1, %2" : "=v"(r) : "v"(a), "v"(b));
  return r;
}

#define GLOAD16(src, dst)                                                   \
  __builtin_amdgcn_global_load_lds(                                         \
      (const __attribute__((address_space(1))) uint32_t*)(src),             \
      (__attribute__((address_space(3))) uint32_t*)(dst), 16, 0, 0)

// ---------------------------------------------------------------------------
// Kernel 1: VirtualEmbedding -> bf16 A tiles (4 m-tiles x 12 ks), frag order.
// (unchanged — verified R9-R11)
// ---------------------------------------------------------------------------
__global__ __launch_bounds__(256) void emb_kernel(
    const int* __restrict__ ids, const float* __restrict__ W_emb,
    const float* __restrict__ padding, const int* __restrict__ syn_table,
    const int* __restrict__ syn_mask, char* __restrict__ ws)
{
  const int l = blockIdx.x;
  const int t = threadIdx.x;
  const int id = ids[l];
  int sid[NSYN];
  int msk[NSYN];
#pragma unroll
  for (int k = 0; k < NSYN; ++k) {
    sid[k] = syn_table[id * NSYN + k];
    msk[k] = syn_mask[id * NSYN + k];
  }

  double p[9] = {0, 0, 0, 0, 0, 0, 0, 0, 0};
  for (int d = t; d < EFFECT_DIM; d += 256) {
    p[0] += (double)W_emb[(size_t)id * EFFECT_DIM + d];
#pragma unroll
    for (int k = 0; k < NSYN; ++k)
      p[k + 1] += (double)W_emb[(size_t)sid[k] * EFFECT_DIM + d];
  }

  __shared__ double s_red[9][4];
  const int w = t >> 6;
#pragma unroll
  for (int k = 0; k < 9; ++k) {
    double v = p[k];
#pragma unroll
    for (int off = 32; off > 0; off >>= 1) v += __shfl_down(v, off, 64);
    if ((t & 63) == 0) s_red[k][w] = v;
  }
  __syncthreads();

  const double isum = s_red[0][0] + s_red[0][1] + s_red[0][2] + s_red[0][3];
  float coef[NSYN];
#pragma unroll
  for (int k = 0; k < NSYN; ++k) {
    double ss = s_red[k + 1][0] + s_red[k + 1][1] + s_red[k + 1][2] + s_red[k + 1][3];
    coef[k] = msk[k] ? (float)(isum / ss) : 0.0f;
  }

  const int r = l & 255;
  char* wbase = ws + (size_t)(l >> 8) * (12 * TILE_B);

  for (int j = t; j < 384; j += 256) {
    const int d0 = 2 * j;
    float v0, v1;
    if (d0 < EFFECT_DIM) {
      const float* bp = W_emb + (size_t)id * EFFECT_DIM + d0;
      v0 = bp[0];
      v1 = bp[1];
#pragma unroll
      for (int k = 0; k < NSYN; ++k) {
        const float* sp = W_emb + (size_t)sid[k] * EFFECT_DIM + d0;
        v0 = fmaf(coef[k], sp[0], v0);
        v1 = fmaf(coef[k], sp[1], v1);
      }
    } else {
      v0 = padding[l * ADD_DIM + (d0 - EFFECT_DIM)];
      v1 = padding[l * ADD_DIM + (d0 + 1 - EFFECT_DIM)];
    }
    const int ks   = j >> 5;
    const int jl   = j & 31;
    const int kk   = jl >> 3;
    const int byte = (jl & 7) * 4;
    const int lane = (r & 31) + ((byte >> 4) << 5);
    *(uint32_t*)(wbase + ks * TILE_B + kk * 8192 + (r >> 5) * 1024 +
                 lane * 16 + (byte & 15)) = pack2(v0, v1);
  }
}

// ---------------------------------------------------------------------------
// Kernel 2 (R12): fused GEMM, M512 x N256 block, 512 threads, 8 waves
// (4m x 2n), wave-tile 128x128 = 4x4 frags -> read/MFMA = 0.5 (the fix for
// the operand-delivery bottleneck that pinned R2-R11 at ~240us).
// LDS 128KB: A 64KB single (2 frag-ordered 32KB tiles via global_load_lds
// from ws, L2-hot) + B 2x32KB dbuf (f32->bf16 inline from W_rev, reg-
// prefetched one ks ahead). Per ks: 64 MFMA/wave vs 32 ds_read_b128 —
// MFMA is the largest pipe. Conv pass deleted.
// ---------------------------------------------------------------------------
__global__ __launch_bounds__(512, 1) void gemm_big(
    const float* __restrict__ Wrev, const char* __restrict__ Abuf,
    float* __restrict__ out)
{
  extern __shared__ char lds[];  // A: [0,64K); B: 64K + buf*32K
  const int t = threadIdx.x;
  const int l = t & 63;
  const int w = t >> 6;        // 0..7
  const int wm = w >> 1;       // 0..3: 128-row m-slice
  const int wn = w & 1;        // 0..1: 128-col n-half

  const int orig = blockIdx.x;           // 744 = 8 x 93, clean remap
  const int xcd  = orig & 7;
  const int work = xcd * 93 + (orig >> 3);
  const int mt = work & 1;               // mt-siblings adjacent -> B L2-shared
  const int nt = work >> 1;              // 0..371
  const int n0 = nt * 256;

  // B staging role: thread owns col sn = t&255, kg = t>>8 (32 k-rows)
  const int sn = t & 255;
  const int kg = t >> 8;       // 0..1 -> kk blocks {2kg, 2kg+1}
  const int gn = n0 + sn;
  const bool valid = gn < NCOLS;

  float br[32];

#define BLOAD(ksi)                                                         \
  {                                                                        \
    const float* p = Wrev + (size_t)((ksi)*64 + kg*32) * NCOLS + gn;       \
    _Pragma("unroll") for (int j = 0; j < 32; ++j)                         \
      br[j] = valid ? p[(size_t)j * NCOLS] : 0.0f;                         \
  }

#define BSTORE(buf)                                                        \
  {                                                                        \
    _Pragma("unroll") for (int c = 0; c < 2; ++c) {                        \
      u32x4 u0, u1;                                                        \
      _Pragma("unroll") for (int j = 0; j < 4; ++j) {                      \
        u0[j] = pack2(br[c*16 + 2*j],     br[c*16 + 2*j + 1]);             \
        u1[j] = pack2(br[c*16 + 8 + 2*j], br[c*16 + 9 + 2*j]);             \
      }                                                                    \
      char* bb = lds + 65536 + (buf)*32768 + (kg*2 + c)*8192 +             \
                 (sn >> 5)*1024;                                           \
      *(u32x4*)(bb + (sn & 31)*16) = u0;                                   \
      *(u32x4*)(bb + ((sn & 31) + 32)*16) = u1;                            \
    }                                                                      \
  }

#define AGLD(ksi)                                                          \
  {                                                                        \
    _Pragma("unroll") for (int tile = 0; tile < 2; ++tile) {               \
      const char* s = Abuf + (size_t)((mt*2 + tile)*12 + (ksi)) * TILE_B   \
                      + t*16;                                              \
      char* d = lds + tile*32768 + w*1024;                                 \
      _Pragma("unroll") for (int i = 0; i < 4; ++i)                        \
        GLOAD16(s + i*8192, d + i*8192);                                   \
    }                                                                      \
  }

  // prologue
  AGLD(0);
  BLOAD(0);
  BSTORE(0);
  __syncthreads();

  // wave fragment bases: rows wm*128 -> A tile (wm>>1), grps (wm&1)*4 + mr
  const char* aw = lds + (wm >> 1)*32768 + ((wm & 1)*4)*1024 + l*16;

  f32x16 acc[4][4] = {};

  for (int ks = 0; ks < 12; ++ks) {
    if (ks < 11) BLOAD(ks + 1);   // T14: f32 loads retire under compute
    const char* bw = lds + 65536 + (ks & 1)*32768 + wn*4096 + l*16;

#pragma unroll
    for (int kk = 0; kk < 4; ++kk) {
      bf16x8 a[4], b[4];
#pragma unroll
      for (int mr = 0; mr < 4; ++mr)
        a[mr] = *(const bf16x8*)(aw + kk*8192 + mr*1024);
#pragma unroll
      for (int nr = 0; nr < 4; ++nr)
        b[nr] = *(const bf16x8*)(bw + kk*8192 + nr*1024);
      __builtin_amdgcn_s_setprio(1);
#pragma unroll
      for (int mr = 0; mr < 4; ++mr)
#pragma unroll
        for (int nr = 0; nr < 4; ++nr)
          acc[mr][nr] = __builtin_amdgcn_mfma_f32_32x32x16_bf16(
              a[mr], b[nr], acc[mr][nr], 0, 0, 0);
      __builtin_amdgcn_s_setprio(0);
    }

    if (ks < 11) {
      BSTORE((ks + 1) & 1);  // writes the non-read B buffer
      __syncthreads();       // all waves done reading A(ks) / B(buf)
      AGLD(ks + 1);          // overwrite A region
      __syncthreads();       // drains vm (A landed) + lgkm (B writes visible)
    }
  }
#undef BLOAD
#undef BSTORE
#undef AGLD

  // epilogue: C layout col=lane&31, row=(reg&3)+8*(reg>>2)+4*(lane>>5)
  const int lh = l >> 5;
#pragma unroll
  for (int nr = 0; nr < 4; ++nr) {
    const int gc = n0 + wn*128 + nr*32 + (l & 31);
    if (gc < NCOLS) {
#pragma unroll
      for (int mr = 0; mr < 4; ++mr)
#pragma unroll
        for (int reg = 0; reg < 16; ++reg) {
          const int row = mt*512 + wm*128 + mr*32 +
                          (reg & 3) + 8*(reg >> 2) + 4*lh;
          out[(size_t)row * NCOLS + gc] = acc[mr][nr][reg];
        }
    }
  }
}

extern "C" void kernel_launch(void* const* d_in, const int* in_sizes, int n_in,
                              void* d_out, int out_size, void* d_ws, size_t ws_size,
                              hipStream_t stream) {
  const int*   ids       = (const int*)d_in[0];
  const float* W_emb     = (const float*)d_in[1];
  const float* W_rev     = (const float*)d_in[2];
  const float* padding   = (const float*)d_in[3];
  const int*   syn_table = (const int*)d_in[4];
  const int*   syn_mask  = (const int*)d_in[5];
  float* out = (float*)d_out;
  char*  ws  = (char*)d_ws;

  // A tiles in ws[0, 1.5MB)
  hipLaunchKernelGGL(emb_kernel, dim3(NROWS), dim3(256), 0, stream,
                     ids, W_emb, padding, syn_table, syn_mask, ws);

  hipLaunchKernelGGL(gemm_big, dim3(NWG), dim3(512), 131072, stream,
                     W_rev, ws, out);
}

// Round 13
// 369.326 us; speedup vs baseline: 30.4299x; 30.4299x over previous
//
#include <hip/hip_runtime.h>
#include <stdint.h>

#define EFFECT_DIM 758
#define ADD_DIM 10
#define EMBED_DIM 768
#define NCOLS 95000
#define NSYN 8
#define NROWS 1024
#define NT256 372            // ceil(95000/256)
#define TILE_B 32768         // 256x64 bf16 tile, fragment-ordered

typedef __attribute__((ext_vector_type(8))) __bf16 bf16x8;
typedef __attribute__((ext_vector_type(16))) float f32x16;
typedef __attribute__((ext_vector_type(4))) uint32_t u32x4;

// Fragment order: tile = [kk 0..3][grp 0..7][lane 0..63] x 16B.
// frag(kk,grp) = 1KB; lane = (row&31) + (khalf8<<5); 16B = 8 consecutive k.
// Conflict-free ds_read_b128 (measured 0 conflicts, R10-R12).

static __device__ __forceinline__ uint32_t pack2(float a, float b) {
  uint32_t r;
  asm("v_cvt_pk_bf16_f32 %0, %1, %2" : "=v"(r) : "v"(a), "v"(b));
  return r;
}

#define GLOAD16(src, dst)                                                   \
  __builtin_amdgcn_global_load_lds(                                         \
      (const __attribute__((address_space(1))) uint32_t*)(src),             \
      (__attribute__((address_space(3))) uint32_t*)(dst), 16, 0, 0)

#define F4C(f, i) ((i) == 0 ? (f).x : (i) == 1 ? (f).y : (i) == 2 ? (f).z : (f).w)

// ---------------------------------------------------------------------------
// Kernel 1: VirtualEmbedding -> bf16 A tiles (4 m-tiles x 12 ks), frag order.
// (verified R9-R12)
// ---------------------------------------------------------------------------
__global__ __launch_bounds__(256) void emb_kernel(
    const int* __restrict__ ids, const float* __restrict__ W_emb,
    const float* __restrict__ padding, const int* __restrict__ syn_table,
    const int* __restrict__ syn_mask, char* __restrict__ ws)
{
  const int l = blockIdx.x;
  const int t = threadIdx.x;
  const int id = ids[l];
  int sid[NSYN];
  int msk[NSYN];
#pragma unroll
  for (int k = 0; k < NSYN; ++k) {
    sid[k] = syn_table[id * NSYN + k];
    msk[k] = syn_mask[id * NSYN + k];
  }

  double p[9] = {0, 0, 0, 0, 0, 0, 0, 0, 0};
  for (int d = t; d < EFFECT_DIM; d += 256) {
    p[0] += (double)W_emb[(size_t)id * EFFECT_DIM + d];
#pragma unroll
    for (int k = 0; k < NSYN; ++k)
      p[k + 1] += (double)W_emb[(size_t)sid[k] * EFFECT_DIM + d];
  }

  __shared__ double s_red[9][4];
  const int w = t >> 6;
#pragma unroll
  for (int k = 0; k < 9; ++k) {
    double v = p[k];
#pragma unroll
    for (int off = 32; off > 0; off >>= 1) v += __shfl_down(v, off, 64);
    if ((t & 63) == 0) s_red[k][w] = v;
  }
  __syncthreads();

  const double isum = s_red[0][0] + s_red[0][1] + s_red[0][2] + s_red[0][3];
  float coef[NSYN];
#pragma unroll
  for (int k = 0; k < NSYN; ++k) {
    double ss = s_red[k + 1][0] + s_red[k + 1][1] + s_red[k + 1][2] + s_red[k + 1][3];
    coef[k] = msk[k] ? (float)(isum / ss) : 0.0f;
  }

  const int r = l & 255;
  char* wbase = ws + (size_t)(l >> 8) * (12 * TILE_B);

  for (int j = t; j < 384; j += 256) {
    const int d0 = 2 * j;
    float v0, v1;
    if (d0 < EFFECT_DIM) {
      const float* bp = W_emb + (size_t)id * EFFECT_DIM + d0;
      v0 = bp[0];
      v1 = bp[1];
#pragma unroll
      for (int k = 0; k < NSYN; ++k) {
        const float* sp = W_emb + (size_t)sid[k] * EFFECT_DIM + d0;
        v0 = fmaf(coef[k], sp[0], v0);
        v1 = fmaf(coef[k], sp[1], v1);
      }
    } else {
      v0 = padding[l * ADD_DIM + (d0 - EFFECT_DIM)];
      v1 = padding[l * ADD_DIM + (d0 + 1 - EFFECT_DIM)];
    }
    const int ks   = j >> 5;
    const int jl   = j & 31;
    const int kk   = jl >> 3;
    const int byte = (jl & 7) * 4;
    const int lane = (r & 31) + ((byte >> 4) << 5);
    *(uint32_t*)(wbase + ks * TILE_B + kk * 8192 + (r >> 5) * 1024 +
                 lane * 16 + (byte & 15)) = pack2(v0, v1);
  }
}

// ---------------------------------------------------------------------------
// Kernel 1b: W_rev f32 -> bf16 B tiles (372 n-tiles x 12 ks), frag order.
// (verified R9: gemm_reg consumed this layout correctly)
// ---------------------------------------------------------------------------
__global__ __launch_bounds__(256) void conv_kernel(
    const float* __restrict__ Wrev, char* __restrict__ Bbuf)
{
  __shared__ char lds[16384];
  const int t   = threadIdx.x;
  const int j   = blockIdx.x;          // 0..743 (128-col half-tiles)
  const int ks  = blockIdx.y;
  const int nl4 = t & 31;
  const int kc  = t >> 5;              // 0..7: 8-k group
  const int gn4 = j * 128 + nl4 * 4;
  const bool valid = (gn4 + 4) <= NCOLS;

  float4 v[8];
  const float* p = Wrev + (size_t)(ks * 64 + kc * 8) * NCOLS + gn4;
#pragma unroll
  for (int jj = 0; jj < 8; ++jj)
    v[jj] = valid ? *(const float4*)(p + (size_t)jj * NCOLS)
                  : float4{0.0f, 0.0f, 0.0f, 0.0f};

  const int kk  = kc >> 1;
  const int lh2 = kc & 1;
#pragma unroll
  for (int i = 0; i < 4; ++i) {
    const int nloc = nl4 * 4 + i;
    u32x4 u;
#pragma unroll
    for (int j2 = 0; j2 < 4; ++j2)
      u[j2] = pack2(F4C(v[2 * j2], i), F4C(v[2 * j2 + 1], i));
    const int lane = (nloc & 31) + (lh2 << 5);
    *(u32x4*)(lds + kk * 4096 + (nl4 >> 3) * 1024 + lane * 16) = u;
  }
  __syncthreads();

  char* base = Bbuf + (size_t)((j >> 1) * 12 + ks) * TILE_B + (j & 1) * 4096;
#pragma unroll
  for (int i = 0; i < 4; ++i) {
    const int idx = i * 4096 + t * 16;
    const int k2  = idx >> 12;
    const int rem = idx & 4095;
    *(u32x4*)(base + k2 * 8192 + rem) = *(const u32x4*)(lds + idx);
  }
}

// ---------------------------------------------------------------------------
// Kernel 2 (R13 = R8 schedule x R9 layout): 256x256 tile, 512 thr, 8 waves
// (2m x 4n), wave 128x64, acc[4][2]. LDS 128KB = 2 sets x (A 32K + B 32K),
// frag-ordered (0 bank conflicts). 4 phases/K-step; phase p: issue stage of
// (T+1, kk=p) [2 GLOAD16/thread], uniform vmcnt(8) -> 4 units stay in
// flight across every barrier; ONE barrier/phase; 6 conflict-free
// ds_read_b128 + 8 MFMA (setprio). T1 remap 1488 = 8 x 186.
// ---------------------------------------------------------------------------
__global__ __launch_bounds__(512, 2) void gemm_pre(
    const char* __restrict__ Abuf, const char* __restrict__ Bbuf,
    float* __restrict__ out)
{
  extern __shared__ char lds[];  // set s at s*65536: [A 32K][B 32K]
  const int t = threadIdx.x;
  const int l = t & 63;
  const int w = t >> 6;
  const int wm = w >> 2;       // 0..1
  const int wn = w & 3;        // 0..3

  const int wgid = blockIdx.x;            // 1488 = 8 x 186
  const int xcd  = wgid & 7;
  const int work = xcd * 186 + (wgid >> 3);
  const int mt = work & 3;
  const int nt = work >> 2;
  const int n0 = nt * 256;

  const char* asrc = Abuf + (size_t)mt * (12 * TILE_B);
  const char* bsrc = Bbuf + (size_t)nt * (12 * TILE_B);
  const int soff = t * 16;                 // linear 8KB unit copy
  const int doff = w * 1024;               // wave-uniform LDS base

  // stage unit kk of tile ks into set s (2 GLOAD16 per thread)
#define STAGEU(s, ksi, kkk)                                                  \
  {                                                                          \
    GLOAD16(asrc + (ksi)*TILE_B + (kkk)*8192 + soff,                         \
            lds + (s)*65536 + (kkk)*8192 + doff);                            \
    GLOAD16(bsrc + (ksi)*TILE_B + (kkk)*8192 + soff,                         \
            lds + (s)*65536 + 32768 + (kkk)*8192 + doff);                    \
  }

  // prologue: all 4 units of tile 0 -> set 0 (8 loads outstanding)
#pragma unroll
  for (int kk = 0; kk < 4; ++kk) STAGEU(0, 0, kk);

  f32x16 acc[4][2] = {};

  for (int T = 0; T < 12; ++T) {
    const int cs = T & 1;
    const char* aw = lds + cs * 65536 + (wm * 4) * 1024 + l * 16;
    const char* bw = lds + cs * 65536 + 32768 + (wn * 2) * 1024 + l * 16;
    const int Tn = (T < 11) ? T + 1 : 11;  // clamped: uniform issue pattern

#pragma unroll
    for (int p = 0; p < 4; ++p) {
      STAGEU(cs ^ 1, Tn, p);               // issue 2 loads (slot not read now)
      asm volatile("s_waitcnt vmcnt(8)" ::: "memory");  // unit (T,p) landed
      __builtin_amdgcn_sched_barrier(0);
      __builtin_amdgcn_s_barrier();        // all waves: unit ready

      bf16x8 a[4], b[2];
#pragma unroll
      for (int mr = 0; mr < 4; ++mr)
        a[mr] = *(const bf16x8*)(aw + p * 8192 + mr * 1024);
#pragma unroll
      for (int nr = 0; nr < 2; ++nr)
        b[nr] = *(const bf16x8*)(bw + p * 8192 + nr * 1024);

      __builtin_amdgcn_s_setprio(1);
#pragma unroll
      for (int mr = 0; mr < 4; ++mr)
#pragma unroll
        for (int nr = 0; nr < 2; ++nr)
          acc[mr][nr] = __builtin_amdgcn_mfma_f32_32x32x16_bf16(
              a[mr], b[nr], acc[mr][nr], 0, 0, 0);
      __builtin_amdgcn_s_setprio(0);
    }
  }
#undef STAGEU

  asm volatile("s_waitcnt vmcnt(0)" ::: "memory");  // drain tail stages

  // epilogue: C layout col=lane&31, row=(reg&3)+8*(reg>>2)+4*(lane>>5)
  const int lh = l >> 5;
#pragma unroll
  for (int nr = 0; nr < 2; ++nr) {
    const int gc = n0 + wn * 64 + nr * 32 + (l & 31);
    if (gc < NCOLS) {
#pragma unroll
      for (int mr = 0; mr < 4; ++mr)
#pragma unroll
        for (int reg = 0; reg < 16; ++reg) {
          const int row = mt * 256 + wm * 128 + mr * 32 +
                          (reg & 3) + 8 * (reg >> 2) + 4 * lh;
          out[(size_t)row * NCOLS + gc] = acc[mr][nr][reg];
        }
    }
  }
}

extern "C" void kernel_launch(void* const* d_in, const int* in_sizes, int n_in,
                              void* d_out, int out_size, void* d_ws, size_t ws_size,
                              hipStream_t stream) {
  const int*   ids       = (const int*)d_in[0];
  const float* W_emb     = (const float*)d_in[1];
  const float* W_rev     = (const float*)d_in[2];
  const float* padding   = (const float*)d_in[3];
  const int*   syn_table = (const int*)d_in[4];
  const int*   syn_mask  = (const int*)d_in[5];
  float* out = (float*)d_out;
  char*  ws  = (char*)d_ws;

  const size_t A_BYTES = (size_t)4 * 12 * TILE_B;        // 1.5 MB
  const size_t B_BYTES = (size_t)NT256 * 12 * TILE_B;    // ~146 MB

  hipLaunchKernelGGL(emb_kernel, dim3(NROWS), dim3(256), 0, stream,
                     ids, W_emb, padding, syn_table, syn_mask, ws);

  if (ws_size >= A_BYTES + B_BYTES) {
    char* Bbuf = ws + A_BYTES;
    hipLaunchKernelGGL(conv_kernel, dim3(NT256 * 2, 12), dim3(256), 0, stream,
                       W_rev, Bbuf);
    // 1488 blocks: 4 m-tiles x 372 n-tiles = 8 XCDs x 186 (bijective)
    hipLaunchKernelGGL(gemm_pre, dim3(4 * NT256), dim3(512), 131072, stream,
                       ws, Bbuf, out);
  } else {
    // (ws is always large enough on this harness; no fallback path exercised)
    hipLaunchKernelGGL(gemm_pre, dim3(4 * NT256), dim3(512), 131072, stream,
                       ws, ws, out);
  }
}

// Round 14
// 343.413 us; speedup vs baseline: 32.7261x; 1.0755x over previous
//
#include <hip/hip_runtime.h>
#include <stdint.h>

#define EFFECT_DIM 758
#define ADD_DIM 10
#define EMBED_DIM 768
#define NCOLS 95000
#define NSYN 8
#define NROWS 1024
#define NT256 372            // ceil(95000/256)
#define TILE_B 32768         // 256x64 bf16 A tile, fragment-ordered

typedef __attribute__((ext_vector_type(8))) __bf16 bf16x8;
typedef __attribute__((ext_vector_type(16))) float f32x16;
typedef __attribute__((ext_vector_type(4))) uint32_t u32x4;

// Fragment order: tile = [kk 0..3][grp 0..7][lane 0..63] x 16B.
// frag(kk,grp) = 1KB; lane = (row&31) + (khalf8<<5); 16B = 8 consecutive k.
// ds_read_b128 on this layout measured 0 bank conflicts (R10-R13).

static __device__ __forceinline__ uint32_t pack2(float a, float b) {
  uint32_t r;
  asm("v_cvt_pk_bf16_f32 %0, %1, %2" : "=v"(r) : "v"(a), "v"(b));
  return r;
}

#define GLOAD16(src, dst)                                                   \
  __builtin_amdgcn_global_load_lds(                                         \
      (const __attribute__((address_space(1))) uint32_t*)(src),             \
      (__attribute__((address_space(3))) uint32_t*)(dst), 16, 0, 0)

// ---------------------------------------------------------------------------
// Kernel 1: VirtualEmbedding -> bf16 A tiles (4 m-tiles x 12 ks), frag order.
// (verified R9-R13)
// ---------------------------------------------------------------------------
__global__ __launch_bounds__(256) void emb_kernel(
    const int* __restrict__ ids, const float* __restrict__ W_emb,
    const float* __restrict__ padding, const int* __restrict__ syn_table,
    const int* __restrict__ syn_mask, char* __restrict__ ws)
{
  const int l = blockIdx.x;
  const int t = threadIdx.x;
  const int id = ids[l];
  int sid[NSYN];
  int msk[NSYN];
#pragma unroll
  for (int k = 0; k < NSYN; ++k) {
    sid[k] = syn_table[id * NSYN + k];
    msk[k] = syn_mask[id * NSYN + k];
  }

  double p[9] = {0, 0, 0, 0, 0, 0, 0, 0, 0};
  for (int d = t; d < EFFECT_DIM; d += 256) {
    p[0] += (double)W_emb[(size_t)id * EFFECT_DIM + d];
#pragma unroll
    for (int k = 0; k < NSYN; ++k)
      p[k + 1] += (double)W_emb[(size_t)sid[k] * EFFECT_DIM + d];
  }

  __shared__ double s_red[9][4];
  const int w = t >> 6;
#pragma unroll
  for (int k = 0; k < 9; ++k) {
    double v = p[k];
#pragma unroll
    for (int off = 32; off > 0; off >>= 1) v += __shfl_down(v, off, 64);
    if ((t & 63) == 0) s_red[k][w] = v;
  }
  __syncthreads();

  const double isum = s_red[0][0] + s_red[0][1] + s_red[0][2] + s_red[0][3];
  float coef[NSYN];
#pragma unroll
  for (int k = 0; k < NSYN; ++k) {
    double ss = s_red[k + 1][0] + s_red[k + 1][1] + s_red[k + 1][2] + s_red[k + 1][3];
    coef[k] = msk[k] ? (float)(isum / ss) : 0.0f;
  }

  const int r = l & 255;
  char* wbase = ws + (size_t)(l >> 8) * (12 * TILE_B);

  for (int j = t; j < 384; j += 256) {
    const int d0 = 2 * j;
    float v0, v1;
    if (d0 < EFFECT_DIM) {
      const float* bp = W_emb + (size_t)id * EFFECT_DIM + d0;
      v0 = bp[0];
      v1 = bp[1];
#pragma unroll
      for (int k = 0; k < NSYN; ++k) {
        const float* sp = W_emb + (size_t)sid[k] * EFFECT_DIM + d0;
        v0 = fmaf(coef[k], sp[0], v0);
        v1 = fmaf(coef[k], sp[1], v1);
      }
    } else {
      v0 = padding[l * ADD_DIM + (d0 - EFFECT_DIM)];
      v1 = padding[l * ADD_DIM + (d0 + 1 - EFFECT_DIM)];
    }
    const int ks   = j >> 5;
    const int jl   = j & 31;
    const int kk   = jl >> 3;
    const int byte = (jl & 7) * 4;
    const int lane = (r & 31) + ((byte >> 4) << 5);
    *(uint32_t*)(wbase + ks * TILE_B + kk * 8192 + (r >> 5) * 1024 +
                 lane * 16 + (byte & 15)) = pack2(v0, v1);
  }
}

// ---------------------------------------------------------------------------
// Kernel 2 (R14): fused GEMM, conv pass deleted. 256x256 tile, 512 thr,
// 8 waves (2m x 4n), wave 128x64, acc[4][2] (AGPR). LDS 128KB = 2 sets x
// [A 32K][B 32K], frag-ordered. One K-step:
//   issue {4 A GLOAD16 + 32 B f32 loads} for T+1   (full-step lead)
//   4 phases x {6 conflict-free ds_read_b128 + 8 MFMA (setprio)}
//   BSTORE: 16 cvt_pk + 4 ds_write_b128 (compiler's exact br vmcnt wait
//           also retires the older A GLOAD16s — in-order vmcnt)
//   lgkmcnt(0); ONE s_barrier.
// 12 barriers total. T1 remap 1488 = 8 x 186 (4 mt-siblings share B panel
// on one XCD -> W_rev f32 read ~once from HBM).
// ---------------------------------------------------------------------------
__global__ __launch_bounds__(512, 2) void gemm_fused(
    const float* __restrict__ Wrev, const char* __restrict__ Abuf,
    float* __restrict__ out)
{
  extern __shared__ char lds[];  // set s at s*65536: [A 32K][B 32K]
  const int t = threadIdx.x;
  const int l = t & 63;
  const int w = t >> 6;
  const int wm = w >> 2;       // 0..1
  const int wn = w & 3;        // 0..3

  const int wgid = blockIdx.x;            // 1488 = 8 x 186
  const int xcd  = wgid & 7;
  const int work = xcd * 186 + (wgid >> 3);
  const int mt = work & 3;
  const int nt = work >> 2;
  const int n0 = nt * 256;

  const char* asrc = Abuf + (size_t)mt * (12 * TILE_B);

  // B staging role: thread owns col sn (0..255), k-rows kg*32..+31
  const int sn = t & 255;
  const int kg = t >> 8;       // 0..1
  const int gn = n0 + sn;
  const bool valid = gn < NCOLS;

  float br[32];

#define AGLD(s, ksi)                                                         \
  {                                                                          \
    _Pragma("unroll") for (int kk = 0; kk < 4; ++kk)                         \
      GLOAD16(asrc + (ksi)*TILE_B + kk*8192 + t*16,                          \
              lds + (s)*65536 + kk*8192 + w*1024);                           \
  }

#define BLOAD(ksi)                                                           \
  {                                                                          \
    const float* p = Wrev + (size_t)((ksi)*64 + kg*32) * NCOLS + gn;         \
    _Pragma("unroll") for (int j = 0; j < 32; ++j)                           \
      br[j] = valid ? p[(size_t)j * NCOLS] : 0.0f;                           \
  }

#define BSTORE(s)                                                            \
  {                                                                          \
    _Pragma("unroll") for (int c = 0; c < 2; ++c) {                          \
      u32x4 u0, u1;                                                          \
      _Pragma("unroll") for (int j = 0; j < 4; ++j) {                        \
        u0[j] = pack2(br[c*16 + 2*j],     br[c*16 + 2*j + 1]);               \
        u1[j] = pack2(br[c*16 + 8 + 2*j], br[c*16 + 9 + 2*j]);               \
      }                                                                      \
      char* bb = lds + (s)*65536 + 32768 + (kg*2 + c)*8192 + (sn>>5)*1024;   \
      *(u32x4*)(bb + (sn & 31)*16) = u0;                                     \
      *(u32x4*)(bb + ((sn & 31) + 32)*16) = u1;                              \
    }                                                                        \
  }

  // prologue: tile 0 -> set 0 (serial; one HBM latency)
  AGLD(0, 0);
  BLOAD(0);
  BSTORE(0);
  asm volatile("s_waitcnt vmcnt(0) lgkmcnt(0)" ::: "memory");
  __builtin_amdgcn_s_barrier();

  f32x16 acc[4][2] = {};

  for (int T = 0; T < 12; ++T) {
    const int cs = T & 1;
    const int Tn = (T < 11) ? T + 1 : 11;  // clamp: uniform, harmless re-stage

    __builtin_amdgcn_sched_barrier(0);
    AGLD(cs ^ 1, Tn);                      // A first (older than B in vm queue)
    BLOAD(Tn);
    __builtin_amdgcn_sched_barrier(0);

    const char* aw = lds + cs * 65536 + (wm * 4) * 1024 + l * 16;
    const char* bw = lds + cs * 65536 + 32768 + (wn * 2) * 1024 + l * 16;

#pragma unroll
    for (int p = 0; p < 4; ++p) {
      bf16x8 a[4], b[2];
#pragma unroll
      for (int mr = 0; mr < 4; ++mr)
        a[mr] = *(const bf16x8*)(aw + p * 8192 + mr * 1024);
#pragma unroll
      for (int nr = 0; nr < 2; ++nr)
        b[nr] = *(const bf16x8*)(bw + p * 8192 + nr * 1024);
      __builtin_amdgcn_s_setprio(1);
#pragma unroll
      for (int mr = 0; mr < 4; ++mr)
#pragma unroll
        for (int nr = 0; nr < 2; ++nr)
          acc[mr][nr] = __builtin_amdgcn_mfma_f32_32x32x16_bf16(
              a[mr], b[nr], acc[mr][nr], 0, 0, 0);
      __builtin_amdgcn_s_setprio(0);
    }

    __builtin_amdgcn_sched_barrier(0);
    BSTORE(cs ^ 1);                        // compiler waits br -> drains A too
    asm volatile("s_waitcnt lgkmcnt(0)" ::: "memory");
    __builtin_amdgcn_sched_barrier(0);
    __builtin_amdgcn_s_barrier();
  }
#undef AGLD
#undef BLOAD
#undef BSTORE

  // epilogue: C layout col=lane&31, row=(reg&3)+8*(reg>>2)+4*(lane>>5)
  const int lh = l >> 5;
#pragma unroll
  for (int nr = 0; nr < 2; ++nr) {
    const int gc = n0 + wn * 64 + nr * 32 + (l & 31);
    if (gc < NCOLS) {
#pragma unroll
      for (int mr = 0; mr < 4; ++mr)
#pragma unroll
        for (int reg = 0; reg < 16; ++reg) {
          const int row = mt * 256 + wm * 128 + mr * 32 +
                          (reg & 3) + 8 * (reg >> 2) + 4 * lh;
          out[(size_t)row * NCOLS + gc] = acc[mr][nr][reg];
        }
    }
  }
}

extern "C" void kernel_launch(void* const* d_in, const int* in_sizes, int n_in,
                              void* d_out, int out_size, void* d_ws, size_t ws_size,
                              hipStream_t stream) {
  const int*   ids       = (const int*)d_in[0];
  const float* W_emb     = (const float*)d_in[1];
  const float* W_rev     = (const float*)d_in[2];
  const float* padding   = (const float*)d_in[3];
  const int*   syn_table = (const int*)d_in[4];
  const int*   syn_mask  = (const int*)d_in[5];
  float* out = (float*)d_out;
  char*  ws  = (char*)d_ws;

  // A tiles in ws[0, 1.5MB); no other workspace needed (conv pass deleted)
  hipLaunchKernelGGL(emb_kernel, dim3(NROWS), dim3(256), 0, stream,
                     ids, W_emb, padding, syn_table, syn_mask, ws);

  // 1488 blocks: 4 m-tiles x 372 n-tiles = 8 XCDs x 186 (bijective)
  hipLaunchKernelGGL(gemm_fused, dim3(4 * NT256), dim3(512), 131072, stream,
                     W_rev, ws, out);
}